// Round 1
// baseline (249.193 us; speedup 1.0000x reference)
//
#include <hip/hip_runtime.h>

typedef __attribute__((ext_vector_type(4))) float f32x4;
typedef __attribute__((ext_vector_type(8))) short bf16x8;
typedef __attribute__((ext_vector_type(4))) unsigned short u16x4;

#define T_DIM 1024
#define B_DIM 8
#define E_DIM 1024
#define H_DIM 16
#define DH 64

__device__ __forceinline__ unsigned short f2bf(float f) {
  unsigned int u = __builtin_bit_cast(unsigned int, f);
  u += 0x7fffu + ((u >> 16) & 1u);   // RNE (inputs are normal floats, no NaN path)
  return (unsigned short)(u >> 16);
}

__device__ __forceinline__ f32x4 mfma16(bf16x8 a, bf16x8 b, f32x4 c) {
  return __builtin_amdgcn_mfma_f32_16x16x32_bf16(a, b, c, 0, 0, 0);
}

// ---------------- cast f32 -> bf16, 4 elems/thread ----------------
__global__ __launch_bounds__(256) void cast_f32_to_bf16(
    const float* __restrict__ src, unsigned short* __restrict__ dst, int n4) {
  int i = blockIdx.x * 256 + threadIdx.x;
  if (i >= n4) return;
  f32x4 v = *(const f32x4*)(src + (size_t)i * 4);
  u16x4 o;
  o[0] = f2bf(v[0]); o[1] = f2bf(v[1]); o[2] = f2bf(v[2]); o[3] = f2bf(v[3]);
  *(u16x4*)(dst + (size_t)i * 4) = o;
}

// ---------------- shared GEMM mainloop ----------------
// C tile 128x128, A [M,K] bf16 K-major, B [N,K] bf16 K-major (B^T layout), BK=32.
// 4 waves (2x2), each wave computes 64x64 = 4x4 fragments of 16x16.
__device__ __forceinline__ void gemm_mainloop(
    const unsigned short* __restrict__ A, const unsigned short* __restrict__ B,
    int K, int m0, int n0, unsigned short* lA, unsigned short* lB, f32x4 acc[4][4]) {
  const int tid = threadIdx.x;
  const int wave = tid >> 6, lane = tid & 63;
  const int lr = lane & 15, lg = lane >> 4;
  const int wr = wave >> 1, wc = wave & 1;
  const int o0 = wave * 1024 + lane * 16;  // linear LDS byte offset, call 0
  for (int k0 = 0; k0 < K; k0 += 32) {
    if (k0) __syncthreads();
#pragma unroll
    for (int c = 0; c < 2; ++c) {
      const int o = c * 4096 + o0;         // byte offset in 8KB tile
      const int row = o >> 6;              // 64B (32 bf16) per tile row
      const int ce = (o & 63) >> 1;        // element offset within row
      __builtin_amdgcn_global_load_lds(
          (const __attribute__((address_space(1))) void*)(A + (size_t)(m0 + row) * K + k0 + ce),
          (__attribute__((address_space(3))) void*)(lA + c * 2048 + wave * 512), 16, 0, 0);
      __builtin_amdgcn_global_load_lds(
          (const __attribute__((address_space(1))) void*)(B + (size_t)(n0 + row) * K + k0 + ce),
          (__attribute__((address_space(3))) void*)(lB + c * 2048 + wave * 512), 16, 0, 0);
    }
    __syncthreads();
    bf16x8 af[4], bfr[4];
#pragma unroll
    for (int i = 0; i < 4; ++i) {
      af[i]  = *(const bf16x8*)(lA + (wr * 64 + i * 16 + lr) * 32 + lg * 8);
      bfr[i] = *(const bf16x8*)(lB + (wc * 64 + i * 16 + lr) * 32 + lg * 8);
    }
#pragma unroll
    for (int mi = 0; mi < 4; ++mi)
#pragma unroll
      for (int ni = 0; ni < 4; ++ni)
        acc[mi][ni] = mfma16(af[mi], bfr[ni], acc[mi][ni]);
  }
}

// ---------------- GEMM1: qkv = query @ qkv_w^T + b, scatter to Q/K/V head layout ----------------
__global__ __launch_bounds__(256) void gemm_qkv(
    const unsigned short* __restrict__ A,   // [8192][1024] bf16 (query, m = t*8+b)
    const unsigned short* __restrict__ W,   // [3072][1024] bf16
    const float* __restrict__ bias,         // [3072] f32
    unsigned short* __restrict__ Qh,        // [128][1024][64] bf16 (pre-scaled)
    unsigned short* __restrict__ Kh,        // [128][1024][64]
    unsigned short* __restrict__ Vh) {      // [128][1024][64]
  __shared__ unsigned short lA[4096], lB[4096];
  f32x4 acc[4][4];
  const f32x4 z4 = {0.f, 0.f, 0.f, 0.f};
#pragma unroll
  for (int i = 0; i < 4; ++i)
#pragma unroll
    for (int j = 0; j < 4; ++j) acc[i][j] = z4;
  const int m0 = blockIdx.x * 128, n0 = blockIdx.y * 128;
  gemm_mainloop(A, W, 1024, m0, n0, lA, lB, acc);

  const int lane = threadIdx.x & 63, wave = threadIdx.x >> 6;
  const int lr = lane & 15, lg = lane >> 4;
  const int wr = wave >> 1, wc = wave & 1;
#pragma unroll
  for (int mi = 0; mi < 4; ++mi)
#pragma unroll
    for (int ni = 0; ni < 4; ++ni)
#pragma unroll
      for (int j = 0; j < 4; ++j) {
        int m = m0 + wr * 64 + mi * 16 + lg * 4 + j;
        int f = n0 + wc * 64 + ni * 16 + lr;
        float v = acc[mi][ni][j] + bias[f];
        int t = m >> 3, b = m & 7;
        int e = f & 1023, h = e >> 6, d = e & 63;
        int which = f >> 10;
        size_t idx = ((size_t)(b * 16 + h) * T_DIM + t) * DH + d;
        if (which == 0)      Qh[idx] = f2bf(v * 0.125f);   // scaling = DH^-0.5
        else if (which == 1) Kh[idx] = f2bf(v);
        else                 Vh[idx] = f2bf(v);
      }
}

// ---------------- V transpose: [n][t][d] -> [n][d][t] ----------------
__global__ __launch_bounds__(256) void transpose_v(
    const unsigned short* __restrict__ Vh, unsigned short* __restrict__ Vt) {
  __shared__ unsigned short tile[64][72];
  const int n = blockIdx.x, t0 = blockIdx.y * 64;
  const int tid = threadIdx.x;
  const int r = tid >> 3, c8 = tid & 7;
#pragma unroll
  for (int it = 0; it < 2; ++it) {
    int row = it * 32 + r;
    bf16x8 v = *(const bf16x8*)(Vh + ((size_t)n * T_DIM + t0 + row) * DH + c8 * 8);
    *(bf16x8*)&tile[row][c8 * 8] = v;
  }
  __syncthreads();
#pragma unroll
  for (int it = 0; it < 2; ++it) {
    int d = it * 32 + r;
    bf16x8 ov;
#pragma unroll
    for (int jj = 0; jj < 8; ++jj) ov[jj] = (short)tile[c8 * 8 + jj][d];
    *(bf16x8*)(Vt + ((size_t)n * DH + d) * T_DIM + t0 + c8 * 8) = ov;
  }
}

// ---------------- flash attention (causal) ----------------
// grid (128 heads, 16 q-tiles of 64), 4 waves; wave handles 16 q rows.
// Q pre-scaled. KV blocks of 64. S/P in reg, P->LDS->A-frag, V from Vt (K-major).
__global__ __launch_bounds__(256) void flash_attn(
    const unsigned short* __restrict__ Qh, const unsigned short* __restrict__ Kh,
    const unsigned short* __restrict__ Vt, unsigned short* __restrict__ attn) {
  __shared__ unsigned short lP[4][16][72];
  const int tid = threadIdx.x;
  const int wave = tid >> 6, lane = tid & 63;
  const int lr = lane & 15, lg = lane >> 4;
  const int n = blockIdx.x;
  const int q0 = blockIdx.y * 64;
  const int b = n >> 4, h = n & 15;
  const int wrb = q0 + wave * 16;

  bf16x8 qf[2];
  {
    const unsigned short* qp = Qh + ((size_t)n * T_DIM + wrb + lr) * DH;
    qf[0] = *(const bf16x8*)(qp + lg * 8);
    qf[1] = *(const bf16x8*)(qp + 32 + lg * 8);
  }
  const f32x4 z4 = {0.f, 0.f, 0.f, 0.f};
  float m_run[4], l_run[4];
  f32x4 o_acc[4];
#pragma unroll
  for (int j = 0; j < 4; ++j) { m_run[j] = -1e30f; l_run[j] = 0.f; }
#pragma unroll
  for (int ci = 0; ci < 4; ++ci) o_acc[ci] = z4;

  for (int s0 = 0; s0 <= q0; s0 += 64) {
    f32x4 s_acc[4] = {z4, z4, z4, z4};
#pragma unroll
    for (int kk = 0; kk < 2; ++kk)
#pragma unroll
      for (int ni = 0; ni < 4; ++ni) {
        bf16x8 kf = *(const bf16x8*)(Kh + ((size_t)n * T_DIM + s0 + ni * 16 + lr) * DH + kk * 32 + lg * 8);
        s_acc[ni] = mfma16(qf[kk], kf, s_acc[ni]);
      }
    if (s0 == q0) {  // only the diagonal block needs masking
#pragma unroll
      for (int ni = 0; ni < 4; ++ni)
#pragma unroll
        for (int j = 0; j < 4; ++j) {
          int col = s0 + ni * 16 + lr;
          int row = wrb + lg * 4 + j;
          if (col > row) s_acc[ni][j] = -10000.0f;  // matches reference masked_bias
        }
    }
    float pt[4][4];
#pragma unroll
    for (int j = 0; j < 4; ++j) {
      float mx = fmaxf(fmaxf(s_acc[0][j], s_acc[1][j]), fmaxf(s_acc[2][j], s_acc[3][j]));
#pragma unroll
      for (int d = 1; d < 16; d <<= 1) mx = fmaxf(mx, __shfl_xor(mx, d));
      float m_new = fmaxf(m_run[j], mx);
      float sc = __expf(m_run[j] - m_new);
      float rs = 0.f;
#pragma unroll
      for (int ni = 0; ni < 4; ++ni) {
        float p = __expf(s_acc[ni][j] - m_new);
        pt[ni][j] = p;
        rs += p;
      }
#pragma unroll
      for (int d = 1; d < 16; d <<= 1) rs += __shfl_xor(rs, d);
      l_run[j] = l_run[j] * sc + rs;
      m_run[j] = m_new;
#pragma unroll
      for (int ci = 0; ci < 4; ++ci) o_acc[ci][j] *= sc;
    }
#pragma unroll
    for (int ni = 0; ni < 4; ++ni)
#pragma unroll
      for (int j = 0; j < 4; ++j) lP[wave][lg * 4 + j][ni * 16 + lr] = f2bf(pt[ni][j]);
    // same-wave LDS write->read: in-order DS pipe + compiler lgkmcnt, no barrier needed
#pragma unroll
    for (int kk = 0; kk < 2; ++kk) {
      bf16x8 pf = *(const bf16x8*)&lP[wave][lr][kk * 32 + lg * 8];
#pragma unroll
      for (int ci = 0; ci < 4; ++ci) {
        bf16x8 vf = *(const bf16x8*)(Vt + ((size_t)n * DH + ci * 16 + lr) * T_DIM + s0 + kk * 32 + lg * 8);
        o_acc[ci] = mfma16(pf, vf, o_acc[ci]);
      }
    }
  }
  float inv[4];
#pragma unroll
  for (int j = 0; j < 4; ++j) inv[j] = 1.0f / l_run[j];
#pragma unroll
  for (int ci = 0; ci < 4; ++ci)
#pragma unroll
    for (int j = 0; j < 4; ++j) {
      int t = wrb + lg * 4 + j;
      int e = h * DH + ci * 16 + lr;
      attn[((size_t)t * B_DIM + b) * E_DIM + e] = f2bf(o_acc[ci][j] * inv[j]);
    }
}

// ---------------- GEMM2: out = attn @ out_w^T + out_b (f32 out) ----------------
__global__ __launch_bounds__(256) void gemm_out(
    const unsigned short* __restrict__ A,   // [8192][1024] bf16 (attn, m = t*8+b)
    const unsigned short* __restrict__ W,   // [1024][1024] bf16
    const float* __restrict__ bias,         // [1024] f32
    float* __restrict__ out) {              // [8192][1024] f32
  __shared__ unsigned short lA[4096], lB[4096];
  f32x4 acc[4][4];
  const f32x4 z4 = {0.f, 0.f, 0.f, 0.f};
#pragma unroll
  for (int i = 0; i < 4; ++i)
#pragma unroll
    for (int j = 0; j < 4; ++j) acc[i][j] = z4;
  const int m0 = blockIdx.x * 128, n0 = blockIdx.y * 128;
  gemm_mainloop(A, W, 1024, m0, n0, lA, lB, acc);

  const int lane = threadIdx.x & 63, wave = threadIdx.x >> 6;
  const int lr = lane & 15, lg = lane >> 4;
  const int wr = wave >> 1, wc = wave & 1;
#pragma unroll
  for (int mi = 0; mi < 4; ++mi)
#pragma unroll
    for (int ni = 0; ni < 4; ++ni)
#pragma unroll
      for (int j = 0; j < 4; ++j) {
        int m = m0 + wr * 64 + mi * 16 + lg * 4 + j;
        int f = n0 + wc * 64 + ni * 16 + lr;
        out[(size_t)m * E_DIM + f] = acc[mi][ni][j] + bias[f];
      }
}

extern "C" void kernel_launch(void* const* d_in, const int* in_sizes, int n_in,
                              void* d_out, int out_size, void* d_ws, size_t ws_size,
                              hipStream_t stream) {
  const float* query = (const float*)d_in[0];
  const float* qkv_w = (const float*)d_in[1];
  const float* qkv_b = (const float*)d_in[2];
  const float* out_w = (const float*)d_in[3];
  const float* out_b = (const float*)d_in[4];
  float* out = (float*)d_out;

  char* ws = (char*)d_ws;
  // workspace layout (bytes):
  //   [0,16M)   query bf16  -> later reused as attn_flat bf16 (dead after gemm_qkv)
  //   [16M,22M) qkv_w bf16
  //   [22M,24M) out_w bf16
  //   [24M,40M) Qh  [128][1024][64]
  //   [40M,56M) Kh
  //   [56M,72M) Vh
  //   [72M,88M) Vt  [128][64][1024]
  unsigned short* Abf  = (unsigned short*)(ws);
  unsigned short* Wbf  = (unsigned short*)(ws + (size_t)(16u << 20));
  unsigned short* OWbf = (unsigned short*)(ws + (size_t)(22u << 20));
  unsigned short* Qh   = (unsigned short*)(ws + (size_t)(24u << 20));
  unsigned short* Kh   = (unsigned short*)(ws + (size_t)(40u << 20));
  unsigned short* Vh   = (unsigned short*)(ws + (size_t)(56u << 20));
  unsigned short* Vt   = (unsigned short*)(ws + (size_t)(72u << 20));
  unsigned short* attn = Abf;  // alias: query-bf16 is dead after gemm_qkv

  cast_f32_to_bf16<<<8192, 256, 0, stream>>>(query, Abf, 8388608 / 4);
  cast_f32_to_bf16<<<3072, 256, 0, stream>>>(qkv_w, Wbf, 3145728 / 4);
  cast_f32_to_bf16<<<1024, 256, 0, stream>>>(out_w, OWbf, 1048576 / 4);
  gemm_qkv<<<dim3(64, 24), 256, 0, stream>>>(Abf, Wbf, qkv_b, Qh, Kh, Vh);
  transpose_v<<<dim3(128, 16), 256, 0, stream>>>(Vh, Vt);
  flash_attn<<<dim3(128, 16), 256, 0, stream>>>(Qh, Kh, Vt, attn);
  gemm_out<<<dim3(64, 8), 256, 0, stream>>>(attn, OWbf, out_b, out);
}

// Round 2
// 189.551 us; speedup vs baseline: 1.3146x; 1.3146x over previous
//
#include <hip/hip_runtime.h>

typedef __attribute__((ext_vector_type(4))) float f32x4;
typedef __attribute__((ext_vector_type(16))) float f32x16;
typedef __attribute__((ext_vector_type(8))) short bf16x8;
typedef __attribute__((ext_vector_type(4))) unsigned short u16x4;
typedef __attribute__((ext_vector_type(4))) unsigned int u32x4;

#define T_DIM 1024
#define B_DIM 8
#define E_DIM 1024
#define H_DIM 16
#define DH 64

__device__ __forceinline__ unsigned short f2bf(float f) {
  unsigned int u = __builtin_bit_cast(unsigned int, f);
  u += 0x7fffu + ((u >> 16) & 1u);   // RNE
  return (unsigned short)(u >> 16);
}

__device__ __forceinline__ unsigned int cvtpk_bf16(float lo, float hi) {
  unsigned int r;
  asm("v_cvt_pk_bf16_f32 %0, %1, %2" : "=v"(r) : "v"(lo), "v"(hi));
  return r;
}

__device__ __forceinline__ f32x4 mfma16(bf16x8 a, bf16x8 b, f32x4 c) {
  return __builtin_amdgcn_mfma_f32_16x16x32_bf16(a, b, c, 0, 0, 0);
}
__device__ __forceinline__ f32x16 mfma32(bf16x8 a, bf16x8 b, f32x16 c) {
  return __builtin_amdgcn_mfma_f32_32x32x16_bf16(a, b, c, 0, 0, 0);
}

// ---------------- cast f32 -> bf16, 4 elems/thread ----------------
__global__ __launch_bounds__(256) void cast_f32_to_bf16(
    const float* __restrict__ src, unsigned short* __restrict__ dst, int n4) {
  int i = blockIdx.x * 256 + threadIdx.x;
  if (i >= n4) return;
  f32x4 v = *(const f32x4*)(src + (size_t)i * 4);
  u16x4 o;
  o[0] = f2bf(v[0]); o[1] = f2bf(v[1]); o[2] = f2bf(v[2]); o[3] = f2bf(v[3]);
  *(u16x4*)(dst + (size_t)i * 4) = o;
}

// ---------------- shared GEMM mainloop (128x128 tile, BK=32) ----------------
__device__ __forceinline__ void gemm_mainloop(
    const unsigned short* __restrict__ A, const unsigned short* __restrict__ B,
    int K, int m0, int n0, unsigned short* lA, unsigned short* lB, f32x4 acc[4][4]) {
  const int tid = threadIdx.x;
  const int wave = tid >> 6, lane = tid & 63;
  const int lr = lane & 15, lg = lane >> 4;
  const int wr = wave >> 1, wc = wave & 1;
  const int o0 = wave * 1024 + lane * 16;
  for (int k0 = 0; k0 < K; k0 += 32) {
    if (k0) __syncthreads();
#pragma unroll
    for (int c = 0; c < 2; ++c) {
      const int o = c * 4096 + o0;
      const int row = o >> 6;
      const int ce = (o & 63) >> 1;
      __builtin_amdgcn_global_load_lds(
          (const __attribute__((address_space(1))) void*)(A + (size_t)(m0 + row) * K + k0 + ce),
          (__attribute__((address_space(3))) void*)(lA + c * 2048 + wave * 512), 16, 0, 0);
      __builtin_amdgcn_global_load_lds(
          (const __attribute__((address_space(1))) void*)(B + (size_t)(n0 + row) * K + k0 + ce),
          (__attribute__((address_space(3))) void*)(lB + c * 2048 + wave * 512), 16, 0, 0);
    }
    __syncthreads();
    bf16x8 af[4], bfr[4];
#pragma unroll
    for (int i = 0; i < 4; ++i) {
      af[i]  = *(const bf16x8*)(lA + (wr * 64 + i * 16 + lr) * 32 + lg * 8);
      bfr[i] = *(const bf16x8*)(lB + (wc * 64 + i * 16 + lr) * 32 + lg * 8);
    }
#pragma unroll
    for (int mi = 0; mi < 4; ++mi)
#pragma unroll
      for (int ni = 0; ni < 4; ++ni)
        acc[mi][ni] = mfma16(af[mi], bfr[ni], acc[mi][ni]);
  }
}

// ---------------- GEMM1: qkv proj, scatter to head layout ----------------
__global__ __launch_bounds__(256) void gemm_qkv(
    const unsigned short* __restrict__ A, const unsigned short* __restrict__ W,
    const float* __restrict__ bias,
    unsigned short* __restrict__ Qh, unsigned short* __restrict__ Kh,
    unsigned short* __restrict__ Vh) {
  __shared__ unsigned short lA[4096], lB[4096];
  f32x4 acc[4][4];
  const f32x4 z4 = {0.f, 0.f, 0.f, 0.f};
#pragma unroll
  for (int i = 0; i < 4; ++i)
#pragma unroll
    for (int j = 0; j < 4; ++j) acc[i][j] = z4;
  const int m0 = blockIdx.x * 128, n0 = blockIdx.y * 128;
  gemm_mainloop(A, W, 1024, m0, n0, lA, lB, acc);

  const int lane = threadIdx.x & 63, wave = threadIdx.x >> 6;
  const int lr = lane & 15, lg = lane >> 4;
  const int wr = wave >> 1, wc = wave & 1;
#pragma unroll
  for (int mi = 0; mi < 4; ++mi)
#pragma unroll
    for (int ni = 0; ni < 4; ++ni)
#pragma unroll
      for (int j = 0; j < 4; ++j) {
        int m = m0 + wr * 64 + mi * 16 + lg * 4 + j;
        int f = n0 + wc * 64 + ni * 16 + lr;
        float v = acc[mi][ni][j] + bias[f];
        int t = m >> 3, b = m & 7;
        int e = f & 1023, h = e >> 6, d = e & 63;
        int which = f >> 10;
        size_t idx = ((size_t)(b * 16 + h) * T_DIM + t) * DH + d;
        if (which == 0)      Qh[idx] = f2bf(v * 0.125f);
        else if (which == 1) Kh[idx] = f2bf(v);
        else                 Vh[idx] = f2bf(v);
      }
}

// ---------------- V transpose: [n][t][d] -> [n][d][t] ----------------
__global__ __launch_bounds__(256) void transpose_v(
    const unsigned short* __restrict__ Vh, unsigned short* __restrict__ Vt) {
  __shared__ unsigned short tile[64][72];
  const int n = blockIdx.x, t0 = blockIdx.y * 64;
  const int tid = threadIdx.x;
  const int r = tid >> 3, c8 = tid & 7;
#pragma unroll
  for (int it = 0; it < 2; ++it) {
    int row = it * 32 + r;
    bf16x8 v = *(const bf16x8*)(Vh + ((size_t)n * T_DIM + t0 + row) * DH + c8 * 8);
    *(bf16x8*)&tile[row][c8 * 8] = v;
  }
  __syncthreads();
#pragma unroll
  for (int it = 0; it < 2; ++it) {
    int d = it * 32 + r;
    bf16x8 ov;
#pragma unroll
    for (int jj = 0; jj < 8; ++jj) ov[jj] = (short)tile[c8 * 8 + jj][d];
    *(bf16x8*)(Vt + ((size_t)n * DH + d) * T_DIM + t0 + c8 * 8) = ov;
  }
}

// ---------------- flash attention v2: swapped-QK^T 32x32, in-register softmax ----------------
// grid: 1024 blocks (qt reversed for LPT) x 4 independent waves; wave = 32 q-rows.
// S^T = K.Q^T (A=K rows=s, B=Q^T cols=q): lane holds 16 scores of q=lane&31 (row split lane<->lane^32).
// O^T = V^T.P^T accumulated in 32 f32 regs; P^T built in-register via cvt_pk + shfl_xor(32).
__global__ __launch_bounds__(256) void flash_attn2(
    const unsigned short* __restrict__ Qh, const unsigned short* __restrict__ Kh,
    const unsigned short* __restrict__ Vt, unsigned short* __restrict__ attn) {
  const int tid = threadIdx.x;
  const int wave = tid >> 6, lane = tid & 63;
  const int lq = lane & 31;            // q column within wave tile
  const int hi = lane >> 5;
  const int bid = blockIdx.x;
  const int qt = 7 - (bid >> 7);       // heaviest q-tiles first
  const int n = bid & 127;
  const int b = n >> 4, h = n & 15;
  const int q0 = qt * 128 + wave * 32;
  const int q = q0 + lq;

  // Q^T B-fragments: qf[kk] holds Q[q][d=16*kk+8*hi+i]
  bf16x8 qf[4];
  const unsigned short* qp = Qh + ((size_t)n * T_DIM + q) * DH + hi * 8;
#pragma unroll
  for (int kk = 0; kk < 4; ++kk) qf[kk] = *(const bf16x8*)(qp + kk * 16);

  f32x16 o0, o1;
#pragma unroll
  for (int r = 0; r < 16; ++r) { o0[r] = 0.f; o1[r] = 0.f; }
  float m_run = -1e30f, l_run = 0.f;

  const unsigned short* kbase = Kh + (size_t)n * T_DIM * DH;
  const unsigned short* vbase = Vt + (size_t)n * DH * T_DIM;

  for (int s0 = 0; s0 < q0 + 32; s0 += 32) {
    // ---- QK^T swapped: S^T[s'][q], s' = (r&3)+8*(r>>2)+4*hi ----
    f32x16 sC;
#pragma unroll
    for (int r = 0; r < 16; ++r) sC[r] = 0.f;
    const unsigned short* kp = kbase + (size_t)(s0 + lq) * DH + hi * 8;
    __builtin_amdgcn_s_setprio(1);
#pragma unroll
    for (int kk = 0; kk < 4; ++kk) {
      bf16x8 kf = *(const bf16x8*)(kp + kk * 16);
      sC = mfma32(kf, qf[kk], sC);
    }
    __builtin_amdgcn_s_setprio(0);
    if (s0 == q0) {  // diagonal tile: mask s' > lq
#pragma unroll
      for (int r = 0; r < 16; ++r) {
        int sp = (r & 3) + 8 * (r >> 2) + 4 * hi;
        if (sp > lq) sC[r] = -10000.0f;   // matches reference masked_bias
      }
    }
    // ---- online softmax, fully in-register per q-row ----
    float tmax = sC[0];
#pragma unroll
    for (int r = 1; r < 16; ++r) tmax = fmaxf(tmax, sC[r]);
    tmax = fmaxf(tmax, __shfl_xor(tmax, 32));
    if (__any(tmax - m_run > 8.0f)) {       // defer-max (T13, THR=8)
      float m_new = fmaxf(m_run, tmax);
      float sc = __expf(m_run - m_new);
      l_run *= sc;
#pragma unroll
      for (int r = 0; r < 16; ++r) { o0[r] *= sc; o1[r] *= sc; }
      m_run = m_new;
    }
    float rs = 0.f;
#pragma unroll
    for (int r = 0; r < 16; ++r) {
      sC[r] = __expf(sC[r] - m_run);
      rs += sC[r];
    }
    rs += __shfl_xor(rs, 32);
    l_run += rs;
    // ---- pack P^T to bf16 B-fragments (cvt_pk + cross-32 exchange) ----
    unsigned int pk[8];
#pragma unroll
    for (int i = 0; i < 8; ++i) pk[i] = cvtpk_bf16(sC[2 * i], sC[2 * i + 1]);
    const unsigned short* vp = vbase + (size_t)lq * T_DIM + s0 + hi * 8;
    __builtin_amdgcn_s_setprio(1);
#pragma unroll
    for (int ks = 0; ks < 2; ++ks) {
      unsigned int A0 = pk[ks * 4 + 0], A1 = pk[ks * 4 + 1];
      unsigned int B0 = pk[ks * 4 + 2], B1 = pk[ks * 4 + 3];
      unsigned int xA0 = __shfl_xor(A0, 32), xA1 = __shfl_xor(A1, 32);
      unsigned int xB0 = __shfl_xor(B0, 32), xB1 = __shfl_xor(B1, 32);
      u32x4 uu;
      uu[0] = hi ? xB0 : A0;
      uu[1] = hi ? xB1 : A1;
      uu[2] = hi ? B0 : xA0;
      uu[3] = hi ? B1 : xA1;
      bf16x8 pf = __builtin_bit_cast(bf16x8, uu);
      bf16x8 v0 = *(const bf16x8*)(vp + ks * 16);
      bf16x8 v1 = *(const bf16x8*)(vp + 32 * T_DIM + ks * 16);
      o0 = mfma32(v0, pf, o0);
      o1 = mfma32(v1, pf, o1);
    }
    __builtin_amdgcn_s_setprio(0);
  }

  const float inv = 1.0f / l_run;
  unsigned short* op = attn + ((size_t)q * B_DIM + b) * E_DIM + h * DH;
#pragma unroll
  for (int g = 0; g < 4; ++g) {
    u16x4 w0, w1;
#pragma unroll
    for (int j = 0; j < 4; ++j) {
      w0[j] = f2bf(o0[g * 4 + j] * inv);
      w1[j] = f2bf(o1[g * 4 + j] * inv);
    }
    int d = 8 * g + 4 * hi;
    *(u16x4*)(op + d) = w0;
    *(u16x4*)(op + 32 + d) = w1;
  }
}

// ---------------- GEMM2: out = attn @ out_w^T + out_b (f32 out) ----------------
__global__ __launch_bounds__(256) void gemm_out(
    const unsigned short* __restrict__ A, const unsigned short* __restrict__ W,
    const float* __restrict__ bias, float* __restrict__ out) {
  __shared__ unsigned short lA[4096], lB[4096];
  f32x4 acc[4][4];
  const f32x4 z4 = {0.f, 0.f, 0.f, 0.f};
#pragma unroll
  for (int i = 0; i < 4; ++i)
#pragma unroll
    for (int j = 0; j < 4; ++j) acc[i][j] = z4;
  const int m0 = blockIdx.x * 128, n0 = blockIdx.y * 128;
  gemm_mainloop(A, W, 1024, m0, n0, lA, lB, acc);

  const int lane = threadIdx.x & 63, wave = threadIdx.x >> 6;
  const int lr = lane & 15, lg = lane >> 4;
  const int wr = wave >> 1, wc = wave & 1;
#pragma unroll
  for (int mi = 0; mi < 4; ++mi)
#pragma unroll
    for (int ni = 0; ni < 4; ++ni)
#pragma unroll
      for (int j = 0; j < 4; ++j) {
        int m = m0 + wr * 64 + mi * 16 + lg * 4 + j;
        int f = n0 + wc * 64 + ni * 16 + lr;
        out[(size_t)m * E_DIM + f] = acc[mi][ni][j] + bias[f];
      }
}

extern "C" void kernel_launch(void* const* d_in, const int* in_sizes, int n_in,
                              void* d_out, int out_size, void* d_ws, size_t ws_size,
                              hipStream_t stream) {
  const float* query = (const float*)d_in[0];
  const float* qkv_w = (const float*)d_in[1];
  const float* qkv_b = (const float*)d_in[2];
  const float* out_w = (const float*)d_in[3];
  const float* out_b = (const float*)d_in[4];
  float* out = (float*)d_out;

  char* ws = (char*)d_ws;
  unsigned short* Abf  = (unsigned short*)(ws);
  unsigned short* Wbf  = (unsigned short*)(ws + (size_t)(16u << 20));
  unsigned short* OWbf = (unsigned short*)(ws + (size_t)(22u << 20));
  unsigned short* Qh   = (unsigned short*)(ws + (size_t)(24u << 20));
  unsigned short* Kh   = (unsigned short*)(ws + (size_t)(40u << 20));
  unsigned short* Vh   = (unsigned short*)(ws + (size_t)(56u << 20));
  unsigned short* Vt   = (unsigned short*)(ws + (size_t)(72u << 20));
  unsigned short* attn = Abf;  // alias: query-bf16 dead after gemm_qkv

  cast_f32_to_bf16<<<8192, 256, 0, stream>>>(query, Abf, 8388608 / 4);
  cast_f32_to_bf16<<<3072, 256, 0, stream>>>(qkv_w, Wbf, 3145728 / 4);
  cast_f32_to_bf16<<<1024, 256, 0, stream>>>(out_w, OWbf, 1048576 / 4);
  gemm_qkv<<<dim3(64, 24), 256, 0, stream>>>(Abf, Wbf, qkv_b, Qh, Kh, Vh);
  transpose_v<<<dim3(128, 16), 256, 0, stream>>>(Vh, Vt);
  flash_attn2<<<1024, 256, 0, stream>>>(Qh, Kh, Vt, attn);
  gemm_out<<<dim3(64, 8), 256, 0, stream>>>(attn, OWbf, out_b, out);
}